// Round 1
// baseline (719.100 us; speedup 1.0000x reference)
//
#include <hip/hip_runtime.h>

// DiagLinear: out[t][o*16+p] = sum_i x[t][p*256+i] * W[p][o][i] + bias[o*16+p]
// t in [0,16384), o in [0,256), p in [0,16), i in [0,256)
//
// R3: latency-bound fix. Replace the monolithic 131KB LDS tile (1 block/CU,
// serial stage->sync->compute phases, vmcnt-draining __syncthreads) with
// per-p fp32 slice quad-buffering:
//   - 4 x 16.6KB LDS buffers, slices DMA'd 3 iterations ahead via
//     global_load_lds (async, no VGPRs, no staging VALU burst)
//   - raw s_barrier + counted s_waitcnt vmcnt(16) per iteration: B prefetch
//     loads and slice DMAs stay in flight ACROSS barriers (T3/T4 pattern)
//   - fp32->bf16 conversion at fragment build (v_cvt_pk_bf16_f32, 32/iter)
//   - 256-thread blocks (4 waves, wave owns 4 o-strips) -> 65KB LDS ->
//     2 independent blocks/CU instead of one phase-locked 512-thread block
// Fragment/epilogue index math identical to the verified R2 kernel.

typedef __attribute__((ext_vector_type(4))) float f32x4;
typedef __attribute__((ext_vector_type(8))) short short8;

#define SLICE_STRIDE 1040                  // 256 fp32 (1024B) + 16B pad: quad-uniform banks
#define BUF_BYTES    (16 * SLICE_STRIDE)   // 16640 B per slice buffer
#define NBUF         4                     // (g+k)%4 == (p+k)&3 -> compile-time buffer index
#define LDS_TOTAL    (NBUF * BUF_BYTES)    // 66560 B -> 2 blocks/CU (133KB/160KB)

// round-to-nearest-even fp32 -> bf16, packed pair (weight-convert kernel)
__device__ __forceinline__ unsigned int pk2(float a, float b) {
  union { float f; unsigned int u; } x, y;
  x.f = a; y.f = b;
  unsigned int ua = x.u + (0x7fffu + ((x.u >> 16) & 1u));
  unsigned int ub = y.u + (0x7fffu + ((y.u >> 16) & 1u));
  return (ua >> 16) | (ub & 0xffff0000u);
}

// hardware packed cvt (also RNE -> bit-identical to pk2)
__device__ __forceinline__ unsigned int cvtpk(float a, float b) {
  unsigned int r;
  asm("v_cvt_pk_bf16_f32 %0, %1, %2" : "=v"(r) : "v"(a), "v"(b));
  return r;
}

__device__ __forceinline__ void dma_row(const float* g, char* l) {
  // wave-uniform LDS base; HW adds lane*16. 64 lanes x 16B = 1KB = one fp32 slice row.
  __builtin_amdgcn_global_load_lds(
      (const __attribute__((address_space(1))) unsigned int*)g,
      (__attribute__((address_space(3))) unsigned int*)l, 16, 0, 0);
}

__global__ __launch_bounds__(256) void wconv_kernel(
    const float* __restrict__ w, unsigned int* __restrict__ o) {
  int i = blockIdx.x * 256 + threadIdx.x;   // 4 floats -> 2 uints per thread
  float4 f = ((const float4*)w)[i];
  uint2 u;
  u.x = pk2(f.x, f.y);
  u.y = pk2(f.z, f.w);
  ((uint2*)o)[i] = u;
}

__global__ __launch_bounds__(256, 2) void diag_gemm_kernel(
    const float* __restrict__ x, const unsigned short* __restrict__ wb,
    const float* __restrict__ bias, float* __restrict__ out) {
  extern __shared__ char lds[];
  const int tid = threadIdx.x;
  const int wv  = tid >> 6;        // wave 0..3
  const int l   = tid & 63;
  const long T0 = (long)blockIdx.x * 16;

  const int n  = l & 15;           // MFMA col (o_local) / A token row
  const int kg = l >> 4;           // k-group

  const int C0 = (wv * 16 + n) * 256 + kg * 8;            // B lane offset (elements)
  const float* xrow0 = x + (T0 + wv * 4) * 4096 + l * 4;  // this wave's DMA rows base

  short8 a[8], b[2][8];

  // ---- prologue: async-DMA slices 0,1,2 into bufs 0,1,2; prefetch b(0) ----
#pragma unroll
  for (int sl = 0; sl < 3; ++sl) {
#pragma unroll
    for (int i = 0; i < 4; ++i)
      dma_row(xrow0 + i * 4096 + sl * 256,
              lds + sl * BUF_BYTES + (wv * 4 + i) * SLICE_STRIDE);
  }
  __builtin_amdgcn_sched_barrier(0);   // keep b(0) loads AFTER the DMAs (vmcnt count)
  {
    const unsigned short* bp = wb + C0;
#pragma unroll
    for (int ks = 0; ks < 8; ++ks) b[0][ks] = *(const short8*)(bp + ks * 32);
  }
  __builtin_amdgcn_sched_barrier(0);
  asm volatile("s_waitcnt vmcnt(16)" ::: "memory");  // DMA(0) retired; DMA(1,2)+b(0) in flight
  __builtin_amdgcn_s_barrier();
  __builtin_amdgcn_sched_barrier(0);

  float* obase = out + T0 * 4096;

  for (int s = 0; s < 4; ++s) {      // 4 o-strips per wave, sequential
    f32x4 res[16];
#pragma unroll
    for (int p = 0; p < 16; ++p) {   // g = s*16+p; slice(g) ready in buf[p&3]
      const int cur = p & 1, nxt = cur ^ 1;

      // ---- A fragments: fp32 slice -> bf16 regs (RNE) ----
      const char* ab = lds + (p & 3) * BUF_BYTES + n * SLICE_STRIDE + kg * 32;
#pragma unroll
      for (int ks = 0; ks < 8; ++ks) {
        f32x4 lo = *(const f32x4*)(ab + ks * 128);
        f32x4 hi = *(const f32x4*)(ab + ks * 128 + 16);
        union { unsigned int u[4]; short8 s8; } t;
        t.u[0] = cvtpk(lo[0], lo[1]);
        t.u[1] = cvtpk(lo[2], lo[3]);
        t.u[2] = cvtpk(hi[0], hi[1]);
        t.u[3] = cvtpk(hi[2], hi[3]);
        a[ks] = t.s8;
      }

      // ---- prefetch B for g+1 (stays in flight across the barrier) ----
      if (p != 15) {
        const unsigned short* bp = wb + C0 + s * 16384 + (p + 1) * 65536;
#pragma unroll
        for (int ks = 0; ks < 8; ++ks) b[nxt][ks] = *(const short8*)(bp + ks * 32);
      } else if (s != 3) {
        const unsigned short* bp = wb + C0 + (s + 1) * 16384;   // next strip, p=0
#pragma unroll
        for (int ks = 0; ks < 8; ++ks) b[nxt][ks] = *(const short8*)(bp + ks * 32);
      }

      // ---- async-DMA slice g+3 into buf[(p+3)&3] (last read at g-1, pre-barrier) ----
      if (p < 13 || s != 3) {
        const int p3 = (p + 3) & 15;
#pragma unroll
        for (int i = 0; i < 4; ++i)
          dma_row(xrow0 + i * 4096 + p3 * 256,
                  lds + ((p + 3) & 3) * BUF_BYTES + (wv * 4 + i) * SLICE_STRIDE);
      }

      // ---- MFMA chain over k ----
      f32x4 acc = {0.f, 0.f, 0.f, 0.f};
#pragma unroll
      for (int ks = 0; ks < 8; ++ks)
        acc = __builtin_amdgcn_mfma_f32_16x16x32_bf16(a[ks], b[cur][ks], acc, 0, 0, 0);
      res[p] = acc;

      // ---- sync tail: counted vmcnt (never drains b/DMA pipeline) + raw barrier ----
      // steady state: unconsumed after DMA(g+1) = DMA(g+2)[4] + b(g+1)[8] + DMA(g+3)[4] = 16
      if (!(p == 15 && s == 3)) {
        __builtin_amdgcn_sched_barrier(0);
        if (p == 13 && s == 3)      asm volatile("s_waitcnt vmcnt(12)" ::: "memory");
        else if (p == 14 && s == 3) asm volatile("s_waitcnt vmcnt(8)"  ::: "memory");
        else                        asm volatile("s_waitcnt vmcnt(16)" ::: "memory");
        __builtin_amdgcn_s_barrier();
        __builtin_amdgcn_sched_barrier(0);
      }
    }

    // ---- epilogue strip s: lane owns 64B contiguous per row (full sectors) ----
    const int o0 = (wv + 4 * s) * 16;
    const float* bp2 = bias + (o0 + n) * 16;
    float4 bv0 = ((const float4*)bp2)[0];
    float4 bv1 = ((const float4*)bp2)[1];
    float4 bv2 = ((const float4*)bp2)[2];
    float4 bv3 = ((const float4*)bp2)[3];
    float* ob = obase + (long)(o0 + n) * 16;
#pragma unroll
    for (int r = 0; r < 4; ++r) {
      float* orow = ob + (long)(kg * 4 + r) * 4096;
      float4 v0 = make_float4(res[0][r] + bv0.x, res[1][r] + bv0.y,
                              res[2][r] + bv0.z, res[3][r] + bv0.w);
      float4 v1 = make_float4(res[4][r] + bv1.x, res[5][r] + bv1.y,
                              res[6][r] + bv1.z, res[7][r] + bv1.w);
      float4 v2 = make_float4(res[8][r] + bv2.x, res[9][r] + bv2.y,
                              res[10][r] + bv2.z, res[11][r] + bv2.w);
      float4 v3 = make_float4(res[12][r] + bv3.x, res[13][r] + bv3.y,
                              res[14][r] + bv3.z, res[15][r] + bv3.w);
      ((float4*)orow)[0] = v0;
      ((float4*)orow)[1] = v1;
      ((float4*)orow)[2] = v2;
      ((float4*)orow)[3] = v3;
    }
  }
}

extern "C" void kernel_launch(void* const* d_in, const int* in_sizes, int n_in,
                              void* d_out, int out_size, void* d_ws, size_t ws_size,
                              hipStream_t stream) {
  const float* x    = (const float*)d_in[0];   // (8,2048,4096) fp32
  const float* w    = (const float*)d_in[1];   // (16,256,256) fp32
  const float* bias = (const float*)d_in[2];   // (4096,) fp32
  float* out = (float*)d_out;
  unsigned int* wb = (unsigned int*)d_ws;      // 2 MB bf16 weights

  (void)hipFuncSetAttribute((const void*)diag_gemm_kernel,
                            hipFuncAttributeMaxDynamicSharedMemorySize, LDS_TOTAL);

  wconv_kernel<<<1024, 256, 0, stream>>>(w, wb);

  diag_gemm_kernel<<<1024, 256, LDS_TOTAL, stream>>>(
      x, (const unsigned short*)wb, bias, out);
}

// Round 2
// 662.866 us; speedup vs baseline: 1.0848x; 1.0848x over previous
//
#include <hip/hip_runtime.h>

// DiagLinear: out[t][o*16+p] = sum_i x[t][p*256+i] * W[p][o][i] + bias[o*16+p]
// t in [0,16384), o in [0,256), p in [0,16), i in [0,256)
//
// R4: p-OUTER / strip-INNER. R3's regression was 4x re-DMA of x (strip loop
// outside p). Since each p is an independent output (not a reduction), we
// hold res[2][16] (128 VGPRs) across the whole p loop:
//   - each x slice DMA'd ONCE (global_load_lds fp32, quad-buffered, 3 ahead)
//   - each A fragment set built ONCE per p, used by BOTH strips (16 MFMAs)
//   - b loads issued BEFORE the DMA each iter -> compiler b-waits land at
//     vmcnt(10)/vmcnt(2), never draining the DMA pipeline
//   - raw s_barrier + counted vmcnt(2); barrier vmcnt guarantees slice p+1
//     retired while slices p+2,p+3 stay in flight
// 512 threads, 8 waves, wave owns strips {wv, wv+8}. Fragment/epilogue index
// math identical to the verified R2/R3 kernels.

typedef __attribute__((ext_vector_type(4))) float f32x4;
typedef __attribute__((ext_vector_type(8))) short short8;

#define SLICE_STRIDE 1040                  // 256 fp32 + 16B pad -> conflict-free b128 reads
#define BUF_BYTES    (16 * SLICE_STRIDE)   // 16640 B per slice
#define NBUF         4
#define LDS_TOTAL    (NBUF * BUF_BYTES)    // 66560 B

// round-to-nearest-even fp32 -> bf16, packed pair (weight-convert kernel)
__device__ __forceinline__ unsigned int pk2(float a, float b) {
  union { float f; unsigned int u; } x, y;
  x.f = a; y.f = b;
  unsigned int ua = x.u + (0x7fffu + ((x.u >> 16) & 1u));
  unsigned int ub = y.u + (0x7fffu + ((y.u >> 16) & 1u));
  return (ua >> 16) | (ub & 0xffff0000u);
}

// hardware packed cvt (RNE -> bit-identical to pk2)
__device__ __forceinline__ unsigned int cvtpk(float a, float b) {
  unsigned int r;
  asm("v_cvt_pk_bf16_f32 %0, %1, %2" : "=v"(r) : "v"(a), "v"(b));
  return r;
}

__device__ __forceinline__ void dma_row(const float* g, char* l) {
  // wave-uniform LDS base; HW adds lane*16. 64 lanes x 16B = 1KB = one slice row.
  __builtin_amdgcn_global_load_lds(
      (const __attribute__((address_space(1))) unsigned int*)g,
      (__attribute__((address_space(3))) unsigned int*)l, 16, 0, 0);
}

__global__ __launch_bounds__(256) void wconv_kernel(
    const float* __restrict__ w, unsigned int* __restrict__ o) {
  int i = blockIdx.x * 256 + threadIdx.x;
  float4 f = ((const float4*)w)[i];
  uint2 u;
  u.x = pk2(f.x, f.y);
  u.y = pk2(f.z, f.w);
  ((uint2*)o)[i] = u;
}

__global__ __launch_bounds__(512, 2) void diag_gemm_kernel(
    const float* __restrict__ x, const unsigned short* __restrict__ wb,
    const float* __restrict__ bias, float* __restrict__ out) {
  extern __shared__ char lds[];
  const int tid = threadIdx.x;
  const int wv  = tid >> 6;        // wave 0..7
  const int l   = tid & 63;
  const long T0 = (long)blockIdx.x * 16;

  const int n  = l & 15;           // MFMA col (o_local) / A token row
  const int kg = l >> 4;           // k-group

  // this wave DMAs token rows wv*2 and wv*2+1; per-lane src includes l*16B
  const float* xdma = x + (T0 + wv * 2) * 4096 + l * 4;

  // B lane bases for the wave's two strips (o0 = wv*16 and (wv+8)*16)
  const unsigned short* b0base = wb + (wv * 16 + n) * 256 + kg * 8;
  const unsigned short* b1base = wb + ((wv + 8) * 16 + n) * 256 + kg * 8;

  short8 a[8], b0[8], b1[8];
  f32x4 res[2][16];

  // ---- prologue: async-DMA slices 0,1,2 into bufs 0,1,2 ----
#pragma unroll
  for (int sl = 0; sl < 3; ++sl) {
    dma_row(xdma + sl * 256,        lds + sl * BUF_BYTES + (wv * 2) * SLICE_STRIDE);
    dma_row(xdma + 4096 + sl * 256, lds + sl * BUF_BYTES + (wv * 2 + 1) * SLICE_STRIDE);
  }
  __builtin_amdgcn_sched_barrier(0);
  asm volatile("s_waitcnt vmcnt(4)" ::: "memory");  // slice 0 retired; 1,2 in flight
  __builtin_amdgcn_s_barrier();
  __builtin_amdgcn_sched_barrier(0);

#pragma unroll
  for (int p = 0; p < 16; ++p) {
    // ---- b loads FIRST (so b-waits never drain the DMAs issued after) ----
    const unsigned short* bp0 = b0base + p * 65536;
    const unsigned short* bp1 = b1base + p * 65536;
#pragma unroll
    for (int ks = 0; ks < 8; ++ks) b0[ks] = *(const short8*)(bp0 + ks * 32);
#pragma unroll
    for (int ks = 0; ks < 8; ++ks) b1[ks] = *(const short8*)(bp1 + ks * 32);
    __builtin_amdgcn_sched_barrier(0);

    // ---- A fragments: fp32 slice p -> bf16 regs (covers b L2 latency) ----
    const char* ab = lds + (p & 3) * BUF_BYTES + n * SLICE_STRIDE + kg * 32;
#pragma unroll
    for (int ks = 0; ks < 8; ++ks) {
      f32x4 lo = *(const f32x4*)(ab + ks * 128);
      f32x4 hi = *(const f32x4*)(ab + ks * 128 + 16);
      union { unsigned int u[4]; short8 s8; } t;
      t.u[0] = cvtpk(lo[0], lo[1]);
      t.u[1] = cvtpk(lo[2], lo[3]);
      t.u[2] = cvtpk(hi[0], hi[1]);
      t.u[3] = cvtpk(hi[2], hi[3]);
      a[ks] = t.s8;
    }
    __builtin_amdgcn_sched_barrier(0);

    // ---- async-DMA slice p+3 (newest VMEM ops -> stay in flight) ----
    if (p < 13) {
      dma_row(xdma + (p + 3) * 256,
              lds + ((p + 3) & 3) * BUF_BYTES + (wv * 2) * SLICE_STRIDE);
      dma_row(xdma + 4096 + (p + 3) * 256,
              lds + ((p + 3) & 3) * BUF_BYTES + (wv * 2 + 1) * SLICE_STRIDE);
    }
    __builtin_amdgcn_sched_barrier(0);

    // ---- 16 MFMAs: one A set, both strips ----
    f32x4 acc0 = (f32x4){0.f, 0.f, 0.f, 0.f};
    f32x4 acc1 = (f32x4){0.f, 0.f, 0.f, 0.f};
#pragma unroll
    for (int ks = 0; ks < 8; ++ks)
      acc0 = __builtin_amdgcn_mfma_f32_16x16x32_bf16(a[ks], b0[ks], acc0, 0, 0, 0);
#pragma unroll
    for (int ks = 0; ks < 8; ++ks)
      acc1 = __builtin_amdgcn_mfma_f32_16x16x32_bf16(a[ks], b1[ks], acc1, 0, 0, 0);
    res[0][p] = acc0;
    res[1][p] = acc1;

    // ---- counted vmcnt + raw barrier: slice p+1 retired, p+2/p+3 in flight ----
    if (p < 15) {
      __builtin_amdgcn_sched_barrier(0);
      if (p < 13) asm volatile("s_waitcnt vmcnt(2)" ::: "memory");
      else        asm volatile("s_waitcnt vmcnt(0)" ::: "memory");
      __builtin_amdgcn_s_barrier();
      __builtin_amdgcn_sched_barrier(0);
    }
  }

  // ---- epilogue: both strips; lane owns 64B contiguous per row ----
  float* obase = out + T0 * 4096;
#pragma unroll
  for (int s = 0; s < 2; ++s) {
    const int o0 = (wv + 8 * s) * 16;
    const float* bp2 = bias + (o0 + n) * 16;
    float4 bv0 = ((const float4*)bp2)[0];
    float4 bv1 = ((const float4*)bp2)[1];
    float4 bv2 = ((const float4*)bp2)[2];
    float4 bv3 = ((const float4*)bp2)[3];
    float* ob = obase + (long)(o0 + n) * 16;
#pragma unroll
    for (int r = 0; r < 4; ++r) {
      float* orow = ob + (long)(kg * 4 + r) * 4096;
      float4 v0 = make_float4(res[s][0][r] + bv0.x, res[s][1][r] + bv0.y,
                              res[s][2][r] + bv0.z, res[s][3][r] + bv0.w);
      float4 v1 = make_float4(res[s][4][r] + bv1.x, res[s][5][r] + bv1.y,
                              res[s][6][r] + bv1.z, res[s][7][r] + bv1.w);
      float4 v2 = make_float4(res[s][8][r] + bv2.x, res[s][9][r] + bv2.y,
                              res[s][10][r] + bv2.z, res[s][11][r] + bv2.w);
      float4 v3 = make_float4(res[s][12][r] + bv3.x, res[s][13][r] + bv3.y,
                              res[s][14][r] + bv3.z, res[s][15][r] + bv3.w);
      ((float4*)orow)[0] = v0;
      ((float4*)orow)[1] = v1;
      ((float4*)orow)[2] = v2;
      ((float4*)orow)[3] = v3;
    }
  }
}

extern "C" void kernel_launch(void* const* d_in, const int* in_sizes, int n_in,
                              void* d_out, int out_size, void* d_ws, size_t ws_size,
                              hipStream_t stream) {
  const float* x    = (const float*)d_in[0];   // (8,2048,4096) fp32
  const float* w    = (const float*)d_in[1];   // (16,256,256) fp32
  const float* bias = (const float*)d_in[2];   // (4096,) fp32
  float* out = (float*)d_out;
  unsigned int* wb = (unsigned int*)d_ws;      // 2 MB bf16 weights

  (void)hipFuncSetAttribute((const void*)diag_gemm_kernel,
                            hipFuncAttributeMaxDynamicSharedMemorySize, LDS_TOTAL);

  wconv_kernel<<<1024, 256, 0, stream>>>(w, wb);

  diag_gemm_kernel<<<1024, 512, LDS_TOTAL, stream>>>(
      x, (const unsigned short*)wb, bias, out);
}